// Round 2
// baseline (936.736 us; speedup 1.0000x reference)
//
#include <hip/hip_runtime.h>
#include <math.h>

#define Bb 32
#define Cc 256
#define Hh 64
#define Ww 64
#define MIP 8
#define HID 256
#define NOUT 14

// ---------------------------------------------------------------------------
// K_A: fused k1+k2.
//  Per block (b,c): row sums (over w) and col sums (over h) of x[b,c,:,:]
//  into S[(b*C+c)*128 + l] (l<64: row sums; l>=64: col sums).
//  The 256th block to finish batch b (device-scope atomic counter) computes
//  yact[b,m,l] = hswish(bn(sum_c ca_w1[m,c] * mean[b,c,l])) -- the old k2 --
//  overlapped with other batches' k1 streaming. S/store -> threadfence ->
//  atomicAdd (release); winner: atomicAdd -> threadfence (acquire) -> read.
// ---------------------------------------------------------------------------
__global__ __launch_bounds__(256) void kA_sums_yact(
    const float* __restrict__ x, float* __restrict__ S,
    const float* __restrict__ w1,
    const float* __restrict__ bng, const float* __restrict__ bnb,
    const float* __restrict__ bnm, const float* __restrict__ bnv,
    float* __restrict__ yact, unsigned int* __restrict__ cnt) {
    const int bc = blockIdx.x;
    const int b = bc >> 8;
    const int t = threadIdx.x;
    __shared__ float rowpart[64][17];  // +1 pad breaks stride-16 conflicts
    __shared__ float colpart[16][64];
    __shared__ float part[2][MIP][128];
    __shared__ int lasta;

    // ---- k1 body (unchanged, proven) ----
    {
        const float4* xp = (const float4*)(x + (size_t)bc * (Hh * Ww));
        const int cw = t & 15;   // column chunk (4 floats)
        const int rb = t >> 4;   // base row 0..15
        float4 v[4];
#pragma unroll
        for (int k = 0; k < 4; ++k) v[k] = xp[t + 256 * k];  // fully coalesced
        float c0 = 0.f, c1 = 0.f, c2 = 0.f, c3 = 0.f;
#pragma unroll
        for (int k = 0; k < 4; ++k) {
            rowpart[rb + 16 * k][cw] = v[k].x + v[k].y + v[k].z + v[k].w;
            c0 += v[k].x; c1 += v[k].y; c2 += v[k].z; c3 += v[k].w;
        }
        colpart[rb][cw * 4 + 0] = c0;
        colpart[rb][cw * 4 + 1] = c1;
        colpart[rb][cw * 4 + 2] = c2;
        colpart[rb][cw * 4 + 3] = c3;
        __syncthreads();
        float* out = S + (size_t)bc * 128;
        if (t < 64) {
            float s = 0.f;
#pragma unroll
            for (int i = 0; i < 16; ++i) s += rowpart[t][i];
            out[t] = s;
        } else if (t < 128) {
            const int w = t - 64;
            float s = 0.f;
#pragma unroll
            for (int g = 0; g < 16; ++g) s += colpart[g][w];
            out[64 + w] = s;
        }
    }
    // barrier drains vmcnt for ALL threads' S stores (stores are in this
    // CU's L2); t0's threadfence then publishes them device-wide.
    __syncthreads();
    if (t == 0) {
        __threadfence();
        lasta = (atomicAdd(&cnt[b], 1u) == (unsigned)(Cc - 1));
    }
    __syncthreads();
    if (!lasta) return;
    __threadfence();  // acquire: invalidate local caches before reading all-c S

    // ---- k2 body (unchanged math) for batch b ----
    {
        const int half = __builtin_amdgcn_readfirstlane(t >> 7);
        const int l = t & 127;
        const float* Sp = S + (size_t)b * Cc * 128 + (size_t)half * 128 * 128 + l;
        const float* wp = w1 + half * 128;  // w1[m*256 + c], c = half*128 + cc
        float a0 = 0.f, a1 = 0.f, a2 = 0.f, a3 = 0.f,
              a4 = 0.f, a5 = 0.f, a6 = 0.f, a7 = 0.f;
#pragma unroll 4
        for (int cc = 0; cc < 128; ++cc) {
            float s = Sp[(size_t)cc * 128];
            a0 += wp[0 * Cc + cc] * s;
            a1 += wp[1 * Cc + cc] * s;
            a2 += wp[2 * Cc + cc] * s;
            a3 += wp[3 * Cc + cc] * s;
            a4 += wp[4 * Cc + cc] * s;
            a5 += wp[5 * Cc + cc] * s;
            a6 += wp[6 * Cc + cc] * s;
            a7 += wp[7 * Cc + cc] * s;
        }
        part[half][0][l] = a0; part[half][1][l] = a1;
        part[half][2][l] = a2; part[half][3][l] = a3;
        part[half][4][l] = a4; part[half][5][l] = a5;
        part[half][6][l] = a6; part[half][7][l] = a7;
        __syncthreads();
        if (t < 128) {
#pragma unroll
            for (int m = 0; m < MIP; ++m) {
                float sum = (part[0][m][l] + part[1][m][l]) * (1.0f / 64.0f);
                float y = (sum - bnm[m]) * (bng[m] / sqrtf(bnv[m] + 1e-5f)) + bnb[m];
                float cl = fminf(fmaxf(y + 3.0f, 0.0f), 6.0f);
                yact[((size_t)b * MIP + m) * 128 + l] = y * cl * (1.0f / 6.0f);
            }
        }
    }
}

// ---------------------------------------------------------------------------
// K_B: fused k3+k4.
//  Per block (b,c): p[b,c] = mean_{h,w}( x * a_h * a_w ), a_h/a_w recomputed
//  from yact. x re-read is L3-resident after K_A. The 256th block to finish
//  batch b runs the FC head + per-(b,e) conic geometry (old k4, verbatim),
//  overlapped with other batches' pooling.
// ---------------------------------------------------------------------------
__device__ inline double softplus_d(double xx) {
    return fmax(xx, 0.0) + log1p(exp(-fabs(xx)));
}

__global__ __launch_bounds__(256) void kB_pool_head(
    const float* __restrict__ x, const float* __restrict__ yact,
    const float* __restrict__ wh, const float* __restrict__ ww,
    float* __restrict__ p,
    const float* __restrict__ fc1_w, const float* __restrict__ fc1_b,
    const float* __restrict__ bn1_g, const float* __restrict__ bn1_b,
    const float* __restrict__ bn1_m, const float* __restrict__ bn1_v,
    const float* __restrict__ fo_w, const float* __restrict__ fo_b,
    const float* __restrict__ Kmat, const float* __restrict__ iris_r,
    float* __restrict__ out, unsigned int* __restrict__ cnt2) {
    const int bc = blockIdx.x;
    const int b = bc >> 8;
    const int c = bc & 255;
    const int t = threadIdx.x;
    __shared__ float ah[64], aw[64], red[4];
    __shared__ float pl[256], hdd[256], raw[16];
    __shared__ float part2[NOUT][16];
    __shared__ int lastf;

    // ---- k3 body (unchanged, proven) ----
    if (t < 128) {
        const float* yb = yact + (size_t)b * MIP * 128;
        const float* wv = (t < 64) ? (wh + c * MIP) : (ww + c * MIP);
        float acc = 0.f;
#pragma unroll
        for (int m = 0; m < MIP; ++m) acc += wv[m] * yb[m * 128 + t];
        float s = 1.0f / (1.0f + expf(-acc));
        if (t < 64) ah[t] = s; else aw[t - 64] = s;
    }
    __syncthreads();
    {
        const float4* xp = (const float4*)(x + (size_t)bc * (Hh * Ww));
        const int cw = t & 15, rb = t >> 4;
        float partial = 0.f;
#pragma unroll
        for (int k = 0; k < 4; ++k) {
            float4 v = xp[t + 256 * k];
            float rd = v.x * aw[cw * 4 + 0] + v.y * aw[cw * 4 + 1] +
                       v.z * aw[cw * 4 + 2] + v.w * aw[cw * 4 + 3];
            partial += ah[rb + 16 * k] * rd;
        }
#pragma unroll
        for (int off = 32; off > 0; off >>= 1) partial += __shfl_down(partial, off, 64);
        if ((t & 63) == 0) red[t >> 6] = partial;
    }
    __syncthreads();
    if (t == 0) {
        p[bc] = (red[0] + red[1] + red[2] + red[3]) * (1.0f / (float)(Hh * Ww));
        __threadfence();  // release own p store (others released theirs likewise)
        lastf = (atomicAdd(&cnt2[b], 1u) == (unsigned)(Cc - 1));
    }
    __syncthreads();
    if (!lastf) return;
    __threadfence();  // acquire: read all 256 p values fresh

    // ---- k4 body (unchanged math) for batch b ----
    pl[t] = p[b * 256 + t];
    __syncthreads();
    // hdd = relu(bn1(p @ fc1_w^T + fc1_b))
    {
        const float4* wrow = (const float4*)(fc1_w + (size_t)t * 256);
        float acc = fc1_b[t];
#pragma unroll 4
        for (int c4 = 0; c4 < 64; ++c4) {
            float4 w4 = wrow[c4];
            acc += w4.x * pl[c4 * 4] + w4.y * pl[c4 * 4 + 1] +
                   w4.z * pl[c4 * 4 + 2] + w4.w * pl[c4 * 4 + 3];
        }
        float ybn = (acc - bn1_m[t]) * (bn1_g[t] / sqrtf(bn1_v[t] + 1e-5f)) + bn1_b[t];
        hdd[t] = fmaxf(ybn, 0.f);
    }
    __syncthreads();
    // raw[o] = fo_b[o] + sum_j fo_w[o,j]*hdd[j], 16 partials per output
    if (t < NOUT * 16) {
        const int o = t >> 4, lane16 = t & 15;
        const float* wo = fo_w + o * HID + lane16;
        float a = 0.f;
#pragma unroll
        for (int j = 0; j < 16; ++j) a += wo[j * 16] * hdd[lane16 + j * 16];
        part2[o][lane16] = a;
    }
    __syncthreads();
    if (t < NOUT) {
        float a = fo_b[t];
#pragma unroll
        for (int i = 0; i < 16; ++i) a += part2[t][i];
        raw[t] = a;
    }
    __syncthreads();
    if (t < 2) {
        const int e = t;
        const float* tv = raw + e * 7;
        double t0 = tv[0], t1 = tv[1], t2 = tv[2], t3 = tv[3],
               t4 = tv[4], t5 = tv[5], t6 = tv[6];
        double cx = t0, cy = t1;
        double ea = softplus_d(t2) + 1e-6;
        double eb = softplus_d(t3) + 1e-6;
        double rr = sqrt(t4 * t4 + t5 * t5) + 1e-8;
        double cth = t4 / rr, sth = t5 / rr;
        double delta = 0.3 * tanh(t6);
        const int be = b * 2 + e;
        out[be * 6 + 0] = (float)cx;
        out[be * 6 + 1] = (float)cy;
        out[be * 6 + 2] = (float)ea;
        out[be * 6 + 3] = (float)eb;
        out[be * 6 + 4] = (float)cth;
        out[be * 6 + 5] = (float)sth;
        out[384 + be] = (float)delta;

        // ct = cos(atan2(sth,cth)) == cth, st == sth (pair already unit-norm)
        double ct = cth, st = sth;
        double ia2 = 1.0 / (ea * ea), ib2 = 1.0 / (eb * eb);
        double A11 = ct * ct * ia2 + st * st * ib2;
        double A22 = st * st * ia2 + ct * ct * ib2;
        double A12 = ct * st * (ia2 - ib2);
        double axp = A11 * cx + A12 * cy;
        double ayp = A12 * cx + A22 * cy;
        double cAc = A11 * cx * cx + 2.0 * A12 * cx * cy + A22 * cy * cy;
        double Cm[3][3] = {{A11, A12, -axp}, {A12, A22, -ayp}, {-axp, -ayp, cAc - 1.0}};
        double Kd[3][3];
        for (int i = 0; i < 3; ++i)
            for (int j = 0; j < 3; ++j) Kd[i][j] = (double)Kmat[b * 9 + i * 3 + j];
        // Cn = K^T * Cm * K
        double M[3][3], Cn[3][3];
        for (int j = 0; j < 3; ++j)
            for (int l = 0; l < 3; ++l) {
                double s = 0.0;
                for (int k = 0; k < 3; ++k) s += Cm[j][k] * Kd[k][l];
                M[j][l] = s;
            }
        for (int i = 0; i < 3; ++i)
            for (int l = 0; l < 3; ++l) {
                double s = 0.0;
                for (int j = 0; j < 3; ++j) s += Kd[j][i] * M[j][l];
                Cn[i][l] = s;
            }
        double Aa = Cn[0][0], Ab = Cn[1][0], Ac = Cn[1][1];
        double A01 = Cn[0][1];
        double u0 = Cn[0][2], u1 = Cn[1][2];
        // mu = solve(A, -u)  (2x2 inverse)
        double det = Aa * Ac - A01 * Ab;
        double mux = (A01 * u1 - Ac * u0) / det;
        double muy = (Ab * u0 - Aa * u1) / det;
        // ---- LAPACK slaev2 on [[Aa,Ab],[Ab,Ac]] (lower triangle, like eigh) ----
        double sm = Aa + Ac, df = Aa - Ac;
        double adf = fabs(df);
        double tb = Ab + Ab, ab = fabs(tb);
        double acmx, acmn;
        if (fabs(Aa) > fabs(Ac)) { acmx = Aa; acmn = Ac; } else { acmx = Ac; acmn = Aa; }
        double rt;
        if (adf > ab)      rt = adf * sqrt(1.0 + (ab / adf) * (ab / adf));
        else if (adf < ab) rt = ab * sqrt(1.0 + (adf / ab) * (adf / ab));
        else               rt = ab * sqrt(2.0);
        double rt1, rt2; int sgn1;
        if (sm < 0.0)      { rt1 = 0.5 * (sm - rt); sgn1 = -1;
                             rt2 = (acmx / rt1) * acmn - (Ab / rt1) * Ab; }
        else if (sm > 0.0) { rt1 = 0.5 * (sm + rt); sgn1 = 1;
                             rt2 = (acmx / rt1) * acmn - (Ab / rt1) * Ab; }
        else               { rt1 = 0.5 * rt; rt2 = -0.5 * rt; sgn1 = 1; }
        double cs; int sgn2;
        if (df >= 0.0) { cs = df + rt; sgn2 = 1; } else { cs = df - rt; sgn2 = -1; }
        double acs = fabs(cs), cs1, sn1;
        if (acs > ab) {
            double ctv = -tb / cs;
            sn1 = 1.0 / sqrt(1.0 + ctv * ctv);
            cs1 = ctv * sn1;
        } else if (ab == 0.0) {
            cs1 = 1.0; sn1 = 0.0;
        } else {
            double tn = -cs / tb;
            cs1 = 1.0 / sqrt(1.0 + tn * tn);
            sn1 = tn * cs1;
        }
        if (sgn1 == sgn2) { double tmp = cs1; cs1 = -sn1; sn1 = tmp; }
        // ssteqr ascending sort: swap iff rt2 < rt1; evec(rt2) = (-sn1, cs1)
        double lam0, lam1, vx, vy;
        if (rt2 < rt1) { lam0 = rt2; lam1 = rt1; vx = -sn1; vy = cs1; }
        else           { lam0 = rt1; lam1 = rt2; vx = cs1;  vy = sn1; }
        // ---- geometry ----
        double a_n = 1.0 / sqrt(fmax(lam0, 1e-12));
        double b_n = 1.0 / sqrt(fmax(lam1, 1e-12));
        a_n = fmax(a_n, 1e-6);
        double Rir = (double)iris_r[b];
        double zz = fmin(fmax(Rir / a_n, 0.5), 1000.0);
        double rnorm = sqrt(mux * mux + muy * muy + 1.0) + 1e-8;
        double ic0 = (mux / rnorm) * zz, ic1 = (muy / rnorm) * zz, ic2 = (1.0 / rnorm) * zz;
        // axis3 = (cos(atan2(vy,vx)), sin(atan2(vy,vx))) == (vx,vy) (unit pair)
        double a3x = vx, a3y = vy;
        double kn = sqrt(a3x * a3x + a3y * a3y) + 1e-8;
        double kx = a3x / kn, ky = a3y / kn;
        // ctl = cos(acos(r)) == r; stl = sin(acos(r)) == sqrt(1-r^2)
        double rba = fmin(fmax(b_n / a_n, 0.0), 1.0);
        double ctl = rba, stl = sqrt(fmax(1.0 - rba * rba, 0.0));
        double nx = ky * stl, ny = -kx * stl, nz = ctl;
        double nn = sqrt(nx * nx + ny * ny + nz * nz) + 1e-8;
        nx /= nn; ny /= nn; nz /= nn;
        out[448 + be * 3 + 0] = (float)ic0;
        out[448 + be * 3 + 1] = (float)ic1;
        out[448 + be * 3 + 2] = (float)ic2;
        out[640 + be * 3 + 0] = (float)nx;
        out[640 + be * 3 + 1] = (float)ny;
        out[640 + be * 3 + 2] = (float)nz;
        out[832 + be * 3 + 0] = (float)(ic0 + delta * nx);
        out[832 + be * 3 + 1] = (float)(ic1 + delta * ny);
        out[832 + be * 3 + 2] = (float)(ic2 + delta * nz);
        out[1024 + be] = (float)zz;
    }
}

extern "C" void kernel_launch(void* const* d_in, const int* in_sizes, int n_in,
                              void* d_out, int out_size, void* d_ws, size_t ws_size,
                              hipStream_t stream) {
    const float* x     = (const float*)d_in[0];
    const float* Kmat  = (const float*)d_in[1];
    const float* iris  = (const float*)d_in[2];
    const float* ca_w1 = (const float*)d_in[3];
    const float* ca_g  = (const float*)d_in[4];
    const float* ca_b  = (const float*)d_in[5];
    const float* ca_m  = (const float*)d_in[6];
    const float* ca_v  = (const float*)d_in[7];
    const float* ca_wh = (const float*)d_in[8];
    const float* ca_ww = (const float*)d_in[9];
    const float* fc1_w = (const float*)d_in[10];
    const float* fc1_b = (const float*)d_in[11];
    const float* bn1_g = (const float*)d_in[12];
    const float* bn1_b = (const float*)d_in[13];
    const float* bn1_m = (const float*)d_in[14];
    const float* bn1_v = (const float*)d_in[15];
    const float* fo_w  = (const float*)d_in[16];
    const float* fo_b  = (const float*)d_in[17];

    float* ws   = (float*)d_ws;
    float* S    = ws;                            // B*C*128   = 1,048,576 floats
    float* yact = S + (size_t)Bb * Cc * 128;     // B*MIP*128 = 32,768 floats
    float* p    = yact + (size_t)Bb * MIP * 128; // B*C       = 8,192 floats
    unsigned int* cnt = (unsigned int*)(p + (size_t)Bb * Cc);  // 64 uints

    // Zero the two per-batch completion-counter arrays (ws is re-poisoned each
    // iteration; this memset is a graph node inside our launch, so counters
    // are correct on every replay).
    hipMemsetAsync(cnt, 0, 2 * Bb * sizeof(unsigned int), stream);

    kA_sums_yact<<<Bb * Cc, 256, 0, stream>>>(x, S, ca_w1, ca_g, ca_b, ca_m,
                                              ca_v, yact, cnt);
    kB_pool_head<<<Bb * Cc, 256, 0, stream>>>(x, yact, ca_wh, ca_ww, p,
                                              fc1_w, fc1_b, bn1_g, bn1_b,
                                              bn1_m, bn1_v, fo_w, fo_b,
                                              Kmat, iris, (float*)d_out,
                                              cnt + Bb);
}

// Round 3
// 259.140 us; speedup vs baseline: 3.6148x; 3.6148x over previous
//
#include <hip/hip_runtime.h>
#include <math.h>

#define Bb 32
#define Cc 256
#define Hh 64
#define Ww 64
#define MIP 8
#define HID 256
#define NOUT 14

// ---------------------------------------------------------------------------
// Kernel 1: per-(b,c) row sums (over w) and col sums (over h) of x[b,c,:,:].
// Output layout S[(b*C+c)*128 + l]: l<64 = sum_w x[h=l,:], l>=64 = sum_h x[:,w=l-64]
// HBM-bound: 128 MB read at ~6.8 TB/s => ~19 us. Do not touch.
// NOTE (R2 post-mortem): do NOT fuse k2 into this via last-block atomics --
// per-block agent-scope __threadfence() costs an L2 writeback across 8 XCDs;
// 8192 of them measured ~450 us (vs ~20 us here). Kernel boundaries flush once.
// ---------------------------------------------------------------------------
__global__ __launch_bounds__(256) void k1_sums(const float* __restrict__ x,
                                               float* __restrict__ S) {
    const int bc = blockIdx.x;
    const float4* xp = (const float4*)(x + (size_t)bc * (Hh * Ww));
    const int t = threadIdx.x;
    const int cw = t & 15;   // column chunk (4 floats)
    const int rb = t >> 4;   // base row 0..15
    __shared__ float rowpart[64][17];  // +1 pad breaks stride-16 conflicts
    __shared__ float colpart[16][64];
    float4 v[4];
#pragma unroll
    for (int k = 0; k < 4; ++k) v[k] = xp[t + 256 * k];  // fully coalesced
    float c0 = 0.f, c1 = 0.f, c2 = 0.f, c3 = 0.f;
#pragma unroll
    for (int k = 0; k < 4; ++k) {
        rowpart[rb + 16 * k][cw] = v[k].x + v[k].y + v[k].z + v[k].w;
        c0 += v[k].x; c1 += v[k].y; c2 += v[k].z; c3 += v[k].w;
    }
    colpart[rb][cw * 4 + 0] = c0;
    colpart[rb][cw * 4 + 1] = c1;
    colpart[rb][cw * 4 + 2] = c2;
    colpart[rb][cw * 4 + 3] = c3;
    __syncthreads();
    float* out = S + (size_t)bc * 128;
    if (t < 64) {
        float s = 0.f;
#pragma unroll
        for (int i = 0; i < 16; ++i) s += rowpart[t][i];
        out[t] = s;
    } else if (t < 128) {
        const int w = t - 64;
        float s = 0.f;
#pragma unroll
        for (int g = 0; g < 16; ++g) s += colpart[g][w];
        out[64 + w] = s;
    }
}

// ---------------------------------------------------------------------------
// Kernel 2: yact[b,m,l] = hswish(bn(sum_c ca_w1[m,c] * mean[b,c,l]))
// R2 tweak: 2 blocks per b (each owns an l-half of 64), 4-way c-quarter split
// per block. Serial chain per thread: 64 iters x 8 FMA (was 128), and 64
// blocks cover 64 CUs (was 32) -- latency-bound kernel, ~2x more parallelism.
// Each S element still loaded once, feeding all 8 m-accumulators.
// H==W==64 so mean scale is uniformly 1/64 for both halves of l.
// ---------------------------------------------------------------------------
__global__ __launch_bounds__(256) void k2_yact(const float* __restrict__ S,
                                               const float* __restrict__ w1,
                                               const float* __restrict__ bng,
                                               const float* __restrict__ bnb,
                                               const float* __restrict__ bnm,
                                               const float* __restrict__ bnv,
                                               float* __restrict__ yact) {
    const int b = blockIdx.x >> 1;        // 0..31
    const int lh = blockIdx.x & 1;        // l-half: 0 or 1
    const int t = threadIdx.x;
    const int q = t >> 6;                 // c-quarter 0..3 (wave-uniform)
    const int lo = t & 63;                // l within half
    const int l = lh * 64 + lo;
    __shared__ float part[4][MIP][64];
    // S[b, c, l] at b*Cc*128 + c*128 + l, c = q*64 + cc
    const float* Sp = S + (size_t)b * Cc * 128 + (size_t)(q * 64) * 128 + l;
    const float* wp = w1 + q * 64;        // w1[m*256 + c]
    float a0 = 0.f, a1 = 0.f, a2 = 0.f, a3 = 0.f,
          a4 = 0.f, a5 = 0.f, a6 = 0.f, a7 = 0.f;
#pragma unroll 4
    for (int cc = 0; cc < 64; ++cc) {
        float s = Sp[(size_t)cc * 128];
        a0 += wp[0 * Cc + cc] * s;
        a1 += wp[1 * Cc + cc] * s;
        a2 += wp[2 * Cc + cc] * s;
        a3 += wp[3 * Cc + cc] * s;
        a4 += wp[4 * Cc + cc] * s;
        a5 += wp[5 * Cc + cc] * s;
        a6 += wp[6 * Cc + cc] * s;
        a7 += wp[7 * Cc + cc] * s;
    }
    part[q][0][lo] = a0; part[q][1][lo] = a1;
    part[q][2][lo] = a2; part[q][3][lo] = a3;
    part[q][4][lo] = a4; part[q][5][lo] = a5;
    part[q][6][lo] = a6; part[q][7][lo] = a7;
    __syncthreads();
    if (t < 64) {
#pragma unroll
        for (int m = 0; m < MIP; ++m) {
            float sum = (part[0][m][t] + part[1][m][t] +
                         part[2][m][t] + part[3][m][t]) * (1.0f / 64.0f);
            float y = (sum - bnm[m]) * (bng[m] / sqrtf(bnv[m] + 1e-5f)) + bnb[m];
            float cl = fminf(fmaxf(y + 3.0f, 0.0f), 6.0f);
            yact[((size_t)b * MIP + m) * 128 + l] = y * cl * (1.0f / 6.0f);
        }
    }
}

// ---------------------------------------------------------------------------
// Kernel 3: p[b,c] = mean_{h,w}( x[b,c,h,w] * a_h[b,c,h] * a_w[b,c,w] )
// a_h / a_w recomputed on the fly from yact (tiny) to avoid 8 MB round-trip.
// Second 128 MB x pass; L3-resident after k1 => BW-bound. Do not touch.
// ---------------------------------------------------------------------------
__global__ __launch_bounds__(256) void k3_pool(const float* __restrict__ x,
                                               const float* __restrict__ yact,
                                               const float* __restrict__ wh,
                                               const float* __restrict__ ww,
                                               float* __restrict__ p) {
    const int bc = blockIdx.x;
    const int b = bc >> 8;
    const int c = bc & 255;
    const int t = threadIdx.x;
    __shared__ float ah[64], aw[64], red[4];
    if (t < 128) {
        const float* yb = yact + (size_t)b * MIP * 128;
        const float* wv = (t < 64) ? (wh + c * MIP) : (ww + c * MIP);
        float acc = 0.f;
#pragma unroll
        for (int m = 0; m < MIP; ++m) acc += wv[m] * yb[m * 128 + t];
        float s = 1.0f / (1.0f + expf(-acc));
        if (t < 64) ah[t] = s; else aw[t - 64] = s;
    }
    __syncthreads();
    const float4* xp = (const float4*)(x + (size_t)bc * (Hh * Ww));
    const int cw = t & 15, rb = t >> 4;
    float partial = 0.f;
#pragma unroll
    for (int k = 0; k < 4; ++k) {
        float4 v = xp[t + 256 * k];
        float rd = v.x * aw[cw * 4 + 0] + v.y * aw[cw * 4 + 1] +
                   v.z * aw[cw * 4 + 2] + v.w * aw[cw * 4 + 3];
        partial += ah[rb + 16 * k] * rd;
    }
#pragma unroll
    for (int off = 32; off > 0; off >>= 1) partial += __shfl_down(partial, off, 64);
    if ((t & 63) == 0) red[t >> 6] = partial;
    __syncthreads();
    if (t == 0) p[bc] = (red[0] + red[1] + red[2] + red[3]) * (1.0f / (float)(Hh * Ww));
}

// ---------------------------------------------------------------------------
// Kernel 4: FC head + per-(b,e) conic geometry (double precision).
// fc_out parallelized over 224 threads (16 partials per output, LDS reduce).
// Eigendecomposition replicates LAPACK slaev2 + ssteqr ascending sort so the
// eigenvector SIGN matches numpy's eigh (the 'normal' output depends on it).
// Transcendental round-trips (atan2->cos/sin, acos->cos/sin) replaced by
// exact identities on already-normalized pairs.
// ---------------------------------------------------------------------------
__device__ inline double softplus_d(double xx) {
    return fmax(xx, 0.0) + log1p(exp(-fabs(xx)));
}

__global__ __launch_bounds__(256) void k4_head(
    const float* __restrict__ p,
    const float* __restrict__ fc1_w, const float* __restrict__ fc1_b,
    const float* __restrict__ bn1_g, const float* __restrict__ bn1_b,
    const float* __restrict__ bn1_m, const float* __restrict__ bn1_v,
    const float* __restrict__ fo_w, const float* __restrict__ fo_b,
    const float* __restrict__ Kmat, const float* __restrict__ iris_r,
    float* __restrict__ out) {
    const int b = blockIdx.x, t = threadIdx.x;
    __shared__ float pl[256], hdd[256], raw[16];
    __shared__ float part2[NOUT][16];
    pl[t] = p[b * 256 + t];
    __syncthreads();
    // hdd = relu(bn1(p @ fc1_w^T + fc1_b))
    const float4* wrow = (const float4*)(fc1_w + (size_t)t * 256);
    float acc = fc1_b[t];
#pragma unroll 4
    for (int c4 = 0; c4 < 64; ++c4) {
        float4 w4 = wrow[c4];
        acc += w4.x * pl[c4 * 4] + w4.y * pl[c4 * 4 + 1] +
               w4.z * pl[c4 * 4 + 2] + w4.w * pl[c4 * 4 + 3];
    }
    float ybn = (acc - bn1_m[t]) * (bn1_g[t] / sqrtf(bn1_v[t] + 1e-5f)) + bn1_b[t];
    hdd[t] = fmaxf(ybn, 0.f);
    __syncthreads();
    // raw[o] = fo_b[o] + sum_j fo_w[o,j]*hdd[j], 16 partials per output
    if (t < NOUT * 16) {
        const int o = t >> 4, lane16 = t & 15;
        const float* wo = fo_w + o * HID + lane16;
        float a = 0.f;
#pragma unroll
        for (int j = 0; j < 16; ++j) a += wo[j * 16] * hdd[lane16 + j * 16];
        part2[o][lane16] = a;
    }
    __syncthreads();
    if (t < NOUT) {
        float a = fo_b[t];
#pragma unroll
        for (int i = 0; i < 16; ++i) a += part2[t][i];
        raw[t] = a;
    }
    __syncthreads();
    if (t < 2) {
        const int e = t;
        const float* tv = raw + e * 7;
        double t0 = tv[0], t1 = tv[1], t2 = tv[2], t3 = tv[3],
               t4 = tv[4], t5 = tv[5], t6 = tv[6];
        double cx = t0, cy = t1;
        double ea = softplus_d(t2) + 1e-6;
        double eb = softplus_d(t3) + 1e-6;
        double rr = sqrt(t4 * t4 + t5 * t5) + 1e-8;
        double cth = t4 / rr, sth = t5 / rr;
        double delta = 0.3 * tanh(t6);
        const int be = b * 2 + e;
        out[be * 6 + 0] = (float)cx;
        out[be * 6 + 1] = (float)cy;
        out[be * 6 + 2] = (float)ea;
        out[be * 6 + 3] = (float)eb;
        out[be * 6 + 4] = (float)cth;
        out[be * 6 + 5] = (float)sth;
        out[384 + be] = (float)delta;

        // ct = cos(atan2(sth,cth)) == cth, st == sth (pair already unit-norm)
        double ct = cth, st = sth;
        double ia2 = 1.0 / (ea * ea), ib2 = 1.0 / (eb * eb);
        double A11 = ct * ct * ia2 + st * st * ib2;
        double A22 = st * st * ia2 + ct * ct * ib2;
        double A12 = ct * st * (ia2 - ib2);
        double axp = A11 * cx + A12 * cy;
        double ayp = A12 * cx + A22 * cy;
        double cAc = A11 * cx * cx + 2.0 * A12 * cx * cy + A22 * cy * cy;
        double Cm[3][3] = {{A11, A12, -axp}, {A12, A22, -ayp}, {-axp, -ayp, cAc - 1.0}};
        double Kd[3][3];
        for (int i = 0; i < 3; ++i)
            for (int j = 0; j < 3; ++j) Kd[i][j] = (double)Kmat[b * 9 + i * 3 + j];
        // Cn = K^T * Cm * K
        double M[3][3], Cn[3][3];
        for (int j = 0; j < 3; ++j)
            for (int l = 0; l < 3; ++l) {
                double s = 0.0;
                for (int k = 0; k < 3; ++k) s += Cm[j][k] * Kd[k][l];
                M[j][l] = s;
            }
        for (int i = 0; i < 3; ++i)
            for (int l = 0; l < 3; ++l) {
                double s = 0.0;
                for (int j = 0; j < 3; ++j) s += Kd[j][i] * M[j][l];
                Cn[i][l] = s;
            }
        double Aa = Cn[0][0], Ab = Cn[1][0], Ac = Cn[1][1];
        double A01 = Cn[0][1];
        double u0 = Cn[0][2], u1 = Cn[1][2];
        // mu = solve(A, -u)  (2x2 inverse)
        double det = Aa * Ac - A01 * Ab;
        double mux = (A01 * u1 - Ac * u0) / det;
        double muy = (Ab * u0 - Aa * u1) / det;
        // ---- LAPACK slaev2 on [[Aa,Ab],[Ab,Ac]] (lower triangle, like eigh) ----
        double sm = Aa + Ac, df = Aa - Ac;
        double adf = fabs(df);
        double tb = Ab + Ab, ab = fabs(tb);
        double acmx, acmn;
        if (fabs(Aa) > fabs(Ac)) { acmx = Aa; acmn = Ac; } else { acmx = Ac; acmn = Aa; }
        double rt;
        if (adf > ab)      rt = adf * sqrt(1.0 + (ab / adf) * (ab / adf));
        else if (adf < ab) rt = ab * sqrt(1.0 + (adf / ab) * (adf / ab));
        else               rt = ab * sqrt(2.0);
        double rt1, rt2; int sgn1;
        if (sm < 0.0)      { rt1 = 0.5 * (sm - rt); sgn1 = -1;
                             rt2 = (acmx / rt1) * acmn - (Ab / rt1) * Ab; }
        else if (sm > 0.0) { rt1 = 0.5 * (sm + rt); sgn1 = 1;
                             rt2 = (acmx / rt1) * acmn - (Ab / rt1) * Ab; }
        else               { rt1 = 0.5 * rt; rt2 = -0.5 * rt; sgn1 = 1; }
        double cs; int sgn2;
        if (df >= 0.0) { cs = df + rt; sgn2 = 1; } else { cs = df - rt; sgn2 = -1; }
        double acs = fabs(cs), cs1, sn1;
        if (acs > ab) {
            double ctv = -tb / cs;
            sn1 = 1.0 / sqrt(1.0 + ctv * ctv);
            cs1 = ctv * sn1;
        } else if (ab == 0.0) {
            cs1 = 1.0; sn1 = 0.0;
        } else {
            double tn = -cs / tb;
            cs1 = 1.0 / sqrt(1.0 + tn * tn);
            sn1 = tn * cs1;
        }
        if (sgn1 == sgn2) { double tmp = cs1; cs1 = -sn1; sn1 = tmp; }
        // ssteqr ascending sort: swap iff rt2 < rt1; evec(rt2) = (-sn1, cs1)
        double lam0, lam1, vx, vy;
        if (rt2 < rt1) { lam0 = rt2; lam1 = rt1; vx = -sn1; vy = cs1; }
        else           { lam0 = rt1; lam1 = rt2; vx = cs1;  vy = sn1; }
        // ---- geometry ----
        double a_n = 1.0 / sqrt(fmax(lam0, 1e-12));
        double b_n = 1.0 / sqrt(fmax(lam1, 1e-12));
        a_n = fmax(a_n, 1e-6);
        double Rir = (double)iris_r[b];
        double zz = fmin(fmax(Rir / a_n, 0.5), 1000.0);
        double rnorm = sqrt(mux * mux + muy * muy + 1.0) + 1e-8;
        double ic0 = (mux / rnorm) * zz, ic1 = (muy / rnorm) * zz, ic2 = (1.0 / rnorm) * zz;
        // axis3 = (cos(atan2(vy,vx)), sin(atan2(vy,vx))) == (vx,vy) (unit pair)
        double a3x = vx, a3y = vy;
        double kn = sqrt(a3x * a3x + a3y * a3y) + 1e-8;
        double kx = a3x / kn, ky = a3y / kn;
        // ctl = cos(acos(r)) == r; stl = sin(acos(r)) == sqrt(1-r^2)
        double rba = fmin(fmax(b_n / a_n, 0.0), 1.0);
        double ctl = rba, stl = sqrt(fmax(1.0 - rba * rba, 0.0));
        double nx = ky * stl, ny = -kx * stl, nz = ctl;
        double nn = sqrt(nx * nx + ny * ny + nz * nz) + 1e-8;
        nx /= nn; ny /= nn; nz /= nn;
        out[448 + be * 3 + 0] = (float)ic0;
        out[448 + be * 3 + 1] = (float)ic1;
        out[448 + be * 3 + 2] = (float)ic2;
        out[640 + be * 3 + 0] = (float)nx;
        out[640 + be * 3 + 1] = (float)ny;
        out[640 + be * 3 + 2] = (float)nz;
        out[832 + be * 3 + 0] = (float)(ic0 + delta * nx);
        out[832 + be * 3 + 1] = (float)(ic1 + delta * ny);
        out[832 + be * 3 + 2] = (float)(ic2 + delta * nz);
        out[1024 + be] = (float)zz;
    }
}

extern "C" void kernel_launch(void* const* d_in, const int* in_sizes, int n_in,
                              void* d_out, int out_size, void* d_ws, size_t ws_size,
                              hipStream_t stream) {
    const float* x     = (const float*)d_in[0];
    const float* Kmat  = (const float*)d_in[1];
    const float* iris  = (const float*)d_in[2];
    const float* ca_w1 = (const float*)d_in[3];
    const float* ca_g  = (const float*)d_in[4];
    const float* ca_b  = (const float*)d_in[5];
    const float* ca_m  = (const float*)d_in[6];
    const float* ca_v  = (const float*)d_in[7];
    const float* ca_wh = (const float*)d_in[8];
    const float* ca_ww = (const float*)d_in[9];
    const float* fc1_w = (const float*)d_in[10];
    const float* fc1_b = (const float*)d_in[11];
    const float* bn1_g = (const float*)d_in[12];
    const float* bn1_b = (const float*)d_in[13];
    const float* bn1_m = (const float*)d_in[14];
    const float* bn1_v = (const float*)d_in[15];
    const float* fo_w  = (const float*)d_in[16];
    const float* fo_b  = (const float*)d_in[17];

    float* ws   = (float*)d_ws;
    float* S    = ws;                          // B*C*128 = 1,048,576 floats
    float* yact = S + (size_t)Bb * Cc * 128;   // B*MIP*128 = 32,768 floats
    float* p    = yact + (size_t)Bb * MIP * 128; // B*C = 8,192 floats

    k1_sums<<<Bb * Cc, 256, 0, stream>>>(x, S);
    k2_yact<<<Bb * 2, 256, 0, stream>>>(S, ca_w1, ca_g, ca_b, ca_m, ca_v, yact);
    k3_pool<<<Bb * Cc, 256, 0, stream>>>(x, yact, ca_wh, ca_ww, p);
    k4_head<<<Bb, 256, 0, stream>>>(p, fc1_w, fc1_b, bn1_g, bn1_b, bn1_m, bn1_v,
                                    fo_w, fo_b, Kmat, iris, (float*)d_out);
}